// Round 8
// baseline (398.282 us; speedup 1.0000x reference)
//
#include <hip/hip_runtime.h>
#include <math.h>

#define NN 8192
#define FIN 128
#define FOUT 64
#define LRELU 0.2f
#define JSPLIT 16
#define JCH (NN / JSPLIT)   // 512
#define HTSTR 520           // halfs; word-stride 260 = 4 mod 32 -> balanced banks
#define PSTRH 520
#define L2E 1.44269504f

typedef _Float16 f16x8 __attribute__((ext_vector_type(8)));
typedef _Float16 f16x4 __attribute__((ext_vector_type(4)));
typedef float f32x4 __attribute__((ext_vector_type(4)));
typedef int i32x4 __attribute__((ext_vector_type(4)));

// workspace layout (float offsets)
#define WS_HT 0                        // H^T as f16 [FOUT][NN] = 262144 floats
#define WS_S1 262144
#define WS_S2 270336
#define WS_S2MAX 278528
#define WS_PACC 278544                 // JSPLIT x NN x FOUT f32 partials (34 MB)
#define WS_LP (WS_PACC + JSPLIT * NN * FOUT)

// ---------------------------------------------------------------------------
// Kernel 1: h = x@W; emit s1=h@a1, s2=h@a2 (f32) and H^T (f16, [feat][row]).
// ---------------------------------------------------------------------------
__global__ __launch_bounds__(256) void k_hs(const float* __restrict__ x,
                                            const float* __restrict__ W,
                                            const float* __restrict__ a,
                                            float* ws) {
  __shared__ float Wl[FIN * FOUT];   // 32 KB
  __shared__ float xl[16 * FIN];     // 8 KB
  __shared__ float hl[16 * FOUT];    // 4 KB
  const int t = threadIdx.x;
  const int i0 = blockIdx.x * 16;

#pragma unroll
  for (int c = 0; c < 8; ++c) {
    const int flat = c * 1024 + t * 4;
    *(float4*)&Wl[flat] = *(const float4*)&W[flat];
  }
#pragma unroll
  for (int c = 0; c < 2; ++c) {
    const int flat = c * 1024 + t * 4;
    *(float4*)&xl[flat] = *(const float4*)&x[(size_t)i0 * FIN + flat];
  }
  __syncthreads();

  const int r = t >> 4;     // local row 0..15
  const int fg = t & 15;    // feat group: feats [4*fg, 4*fg+4)
  float4 acc = make_float4(0.f, 0.f, 0.f, 0.f);
#pragma unroll 4
  for (int k = 0; k < FIN; ++k) {
    const float xv = xl[r * FIN + k];
    const float4 wv = *(const float4*)&Wl[k * FOUT + fg * 4];
    acc.x = fmaf(xv, wv.x, acc.x);
    acc.y = fmaf(xv, wv.y, acc.y);
    acc.z = fmaf(xv, wv.z, acc.z);
    acc.w = fmaf(xv, wv.w, acc.w);
  }

  float v1 = acc.x * a[fg * 4] + acc.y * a[fg * 4 + 1] +
             acc.z * a[fg * 4 + 2] + acc.w * a[fg * 4 + 3];
  float v2 = acc.x * a[FOUT + fg * 4] + acc.y * a[FOUT + fg * 4 + 1] +
             acc.z * a[FOUT + fg * 4 + 2] + acc.w * a[FOUT + fg * 4 + 3];
  v1 += __shfl_xor(v1, 1); v2 += __shfl_xor(v2, 1);
  v1 += __shfl_xor(v1, 2); v2 += __shfl_xor(v2, 2);
  v1 += __shfl_xor(v1, 4); v2 += __shfl_xor(v2, 4);
  v1 += __shfl_xor(v1, 8); v2 += __shfl_xor(v2, 8);
  if (fg == 0) {
    ws[WS_S1 + i0 + r] = v1;
    ws[WS_S2 + i0 + r] = v2;
  }

  // transpose h tile -> H^T (f16) via LDS
  *(float4*)&hl[r * FOUT + fg * 4] = acc;
  __syncthreads();
  _Float16* ht = (_Float16*)(ws + WS_HT);
  if (t < 128) {
    const int f = t >> 1;
    const int off = (t & 1) * 8;
    f16x8 tmp;
#pragma unroll
    for (int u = 0; u < 8; ++u) tmp[u] = (_Float16)hl[(off + u) * FOUT + f];
    *(f16x8*)&ht[(size_t)f * NN + i0 + off] = tmp;
  }
}

// ---------------------------------------------------------------------------
// Kernel 2: S2max = max_j s2[j]  (leaky monotone -> closed-form row max)
// ---------------------------------------------------------------------------
__global__ __launch_bounds__(256) void k_s2max(float* ws) {
  __shared__ float red[256];
  const int t = threadIdx.x;
  float v = -1e30f;
#pragma unroll
  for (int i = 0; i < NN / 256; ++i) v = fmaxf(v, ws[WS_S2 + i * 256 + t]);
  red[t] = v;
  __syncthreads();
  for (int s = 128; s >= 1; s >>= 1) {
    if (t < s) red[t] = fmaxf(red[t], red[t + s]);
    __syncthreads();
  }
  if (t == 0) ws[WS_S2MAX] = red[0];
}

// ---------------------------------------------------------------------------
// Kernel 3: CONTIGUOUS + forced-deep-burst streaming pass.
// Grid: 128 i-bands x 16 j-splits = 2048 blocks, 256 thr (4 waves).
// Wave w owns rows w*16..+15 of a 64x512 tile. Lane l covers cols l*4..+3:
// every adj load inst is a contiguous 1 KB wave access (16 cache lines).
// ALL 32 nt int4 loads issued before ANY consumer; no LDS read / barrier
// between issue and consume (s1 via global+shfl, s2 via 2 global float4).
// Consume writes f16 p to pal (LDS); ONE barrier; MFMA phase from LDS.
// LDS = 130 KB -> 1 block/CU; burst depth replaces wave-count hiding.
// ---------------------------------------------------------------------------
__global__ __launch_bounds__(256, 1) void k_main(const int* __restrict__ adj,
                                                 float* ws) {
  __shared__ __align__(16) _Float16 pal[64 * PSTRH];    // 66560 B
  __shared__ __align__(16) _Float16 htl[FOUT * HTSTR];  // 66560 B

  const int t = threadIdx.x;
  const int ib = blockIdx.x >> 4;
  const int js = blockIdx.x & 15;
  const int i0 = ib * 64;
  const int jc0 = js * JCH;

  const _Float16* ht = (const _Float16*)(ws + WS_HT);

  // stage ht chunk: 64 feats x 512 halfs, coalesced 16B (L3-resident source)
#pragma unroll
  for (int c = 0; c < 16; ++c) {
    const int chunk = c * 256 + t;      // 0..4095
    const int f = chunk >> 6;
    const int off = (chunk & 63) * 8;
    *(f16x8*)&htl[f * HTSTR + off] = *(const f16x8*)&ht[(size_t)f * NN + jc0 + off];
  }

  const int w = t >> 6;     // wave 0..3
  const int l = t & 63;
  const int m16 = l & 15;
  const int r0 = w * 16;    // wave's row band

  // lane-private softmax inputs (global loads, no LDS -> no barrier needed)
  const float s2max = ws[WS_S2MAX];
  const float sv1 = ws[WS_S1 + i0 + r0 + m16];                 // row r0+m16
  const float4 s2a = *(const float4*)&ws[WS_S2 + jc0 + l * 4];         // g=0
  const float4 s2b = *(const float4*)&ws[WS_S2 + jc0 + 256 + l * 4];   // g=1

  // ---- burst: 32 contiguous nt 1KB-insts, all issued before any consume ----
  const int* abase = adj + (size_t)(i0 + r0) * NN + jc0 + l * 4;
  i32x4 av[32];
#pragma unroll
  for (int r = 0; r < 16; ++r) {
#pragma unroll
    for (int g = 0; g < 2; ++g)
      av[r * 2 + g] = __builtin_nontemporal_load(
          (const i32x4*)(abase + (size_t)r * NN + g * 256));
  }

  // ---- consume in issue order: p = adj ? exp(leaky(s1+s2) - m) : 0 ----
#pragma unroll
  for (int r = 0; r < 16; ++r) {
    const float s1r = __shfl(sv1, r);   // broadcast row r's s1 from lane r
    const float tm = s1r + s2max;
    const float mr = fmaxf(tm, LRELU * tm);
    const float mneg = -mr * L2E;
#pragma unroll
    for (int g = 0; g < 2; ++g) {
      const i32x4 a = av[r * 2 + g];
      const float4 s2v = g ? s2b : s2a;
      float e;
      e = s1r + s2v.x; e = fmaxf(e, LRELU * e);
      const _Float16 q0 = a.x ? (_Float16)exp2f(fmaf(e, L2E, mneg)) : (_Float16)0.f;
      e = s1r + s2v.y; e = fmaxf(e, LRELU * e);
      const _Float16 q1 = a.y ? (_Float16)exp2f(fmaf(e, L2E, mneg)) : (_Float16)0.f;
      e = s1r + s2v.z; e = fmaxf(e, LRELU * e);
      const _Float16 q2 = a.z ? (_Float16)exp2f(fmaf(e, L2E, mneg)) : (_Float16)0.f;
      e = s1r + s2v.w; e = fmaxf(e, LRELU * e);
      const _Float16 q3 = a.w ? (_Float16)exp2f(fmaf(e, L2E, mneg)) : (_Float16)0.f;
      f16x4 pv = {q0, q1, q2, q3};
      *(f16x4*)&pal[(r0 + r) * PSTRH + g * 256 + l * 4] = pv;
    }
  }

  __syncthreads();   // the only barrier: all loads already consumed

  // ---- MFMA phase: A-frags + row-sums from pal, B-frags from htl ----
  const int q8 = (l >> 4) * 8;
  f32x4 acc[4];
#pragma unroll
  for (int nf = 0; nf < 4; ++nf) acc[nf] = (f32x4){0.f, 0.f, 0.f, 0.f};
  float lacc = 0.f;

#pragma unroll
  for (int it = 0; it < JCH / 32; ++it) {   // 16 k-steps
    const int kb = it * 32 + q8;
    const f16x8 af = *(const f16x8*)&pal[(r0 + m16) * PSTRH + kb];
    // denominator from the f16-rounded p: cancels rounding in the ratio
#pragma unroll
    for (int u = 0; u < 8; ++u) lacc += (float)af[u];
#pragma unroll
    for (int nf = 0; nf < 4; ++nf) {
      const f16x8 b = *(const f16x8*)&htl[(nf * 16 + m16) * HTSTR + kb];
      acc[nf] = __builtin_amdgcn_mfma_f32_16x16x32_f16(af, b, acc[nf], 0, 0, 0);
    }
  }

  // row-sum partial: reduce lacc across the 4 quads (same m16)
  lacc += __shfl_xor(lacc, 16);
  lacc += __shfl_xor(lacc, 32);
  if (l < 16) ws[WS_LP + js * NN + i0 + r0 + m16] = lacc;

  // acc partials: C/D layout col=lane&15, row=(lane>>4)*4+reg; nt stores
  float* pacc = ws + WS_PACC + (size_t)js * (NN * FOUT);
  const int orow = i0 + r0 + (l >> 4) * 4;
#pragma unroll
  for (int nf = 0; nf < 4; ++nf)
#pragma unroll
    for (int r = 0; r < 4; ++r)
      __builtin_nontemporal_store(
          acc[nf][r], &pacc[(size_t)(orow + r) * FOUT + nf * 16 + m16]);
}

// ---------------------------------------------------------------------------
// Kernel 4: combine j-split partials, normalize, ELU
// ---------------------------------------------------------------------------
__global__ __launch_bounds__(256) void k_combine(const float* __restrict__ ws,
                                                 float* __restrict__ out) {
  const int idx = blockIdx.x * 256 + threadIdx.x;
  const int i = idx >> 6;
  float s = 0.f, l = 0.f;
#pragma unroll
  for (int js = 0; js < JSPLIT; ++js) {
    s += ws[WS_PACC + (size_t)js * (NN * FOUT) + idx];
    l += ws[WS_LP + js * NN + i];
  }
  const float v = s / l;
  out[idx] = v > 0.f ? v : expm1f(v);
}

// ---------------------------------------------------------------------------
extern "C" void kernel_launch(void* const* d_in, const int* in_sizes, int n_in,
                              void* d_out, int out_size, void* d_ws,
                              size_t ws_size, hipStream_t stream) {
  const float* x = (const float*)d_in[0];
  const int* adj = (const int*)d_in[1];
  const float* W = (const float*)d_in[2];
  const float* a = (const float*)d_in[3];
  float* ws = (float*)d_ws;
  float* out = (float*)d_out;

  hipLaunchKernelGGL(k_hs, dim3(NN / 16), dim3(256), 0, stream, x, W, a, ws);
  hipLaunchKernelGGL(k_s2max, dim3(1), dim3(256), 0, stream, ws);
  hipLaunchKernelGGL(k_main, dim3((NN / 64) * JSPLIT), dim3(256), 0, stream,
                     adj, ws);
  hipLaunchKernelGGL(k_combine, dim3(NN * FOUT / 256), dim3(256), 0, stream,
                     ws, out);
}